// Round 11
// baseline (743.602 us; speedup 1.0000x reference)
//
#include <hip/hip_runtime.h>
#include <math.h>

// Problem constants
#define TX 6
#define NB 2
#define NSTA 35
#define PPLANE 1296      // 36*36 padded plane
#define PADW 36

typedef __attribute__((ext_vector_type(8))) _Float16 half8;
typedef __attribute__((ext_vector_type(4))) float f32x4;

__device__ __forceinline__ float sigf(float x) { return 1.0f / (1.0f + __expf(-x)); }

// Async global->LDS DMA, 16B per lane. LDS dest is wave-uniform base + lane*16.
__device__ __forceinline__ void gload_lds16(const void* g, void* l) {
    __builtin_amdgcn_global_load_lds(
        (const __attribute__((address_space(1))) void*)g,
        (__attribute__((address_space(3))) void*)l, 16, 0, 0);
}

// ---------------------------------------------------------------------------
// Weight prep: W (4CH,CTOT,5,5) fp32 gate-block-major ->
// Wk[d][mb][c32][lk][l16][e8] f16 : fragment = 512 f16 (16 m-rows x 32 cin).
// ---------------------------------------------------------------------------
template <int CTOT, int CTOTP, int CH>
__global__ __launch_bounds__(256) void prep_w2(const float* __restrict__ W,
                                               _Float16* __restrict__ Wk) {
    constexpr int M = 4 * CH;
    const int total = 25 * M * CTOTP;
    int i = blockIdx.x * 256 + threadIdx.x;
    if (i >= total) return;
    const int e   = i & 7;
    const int l16 = (i >> 3) & 15;
    const int lk  = (i >> 7) & 3;
    const int c32 = (i >> 9) % (CTOTP / 32);
    const int rest = (i >> 9) / (CTOTP / 32);
    const int mb = rest % (M / 16);
    const int d  = rest / (M / 16);
    const int m = mb * 16 + l16;
    const int cin = c32 * 32 + lk * 8 + e;
    const int hc = m >> 2, g = m & 3;
    float v = 0.f;
    if (cin < CTOT) v = W[((g * CH + hc) * CTOT + cin) * 25 + d];
    Wk[i] = (_Float16)v;
}

// ---------------------------------------------------------------------------
// Transpose Wf1 (1152,256) -> wf1t (256,1152) fp32, once per call.
// Write-coalesced; read stride-1KB (acceptable one-time cost).
// ---------------------------------------------------------------------------
__global__ __launch_bounds__(256) void prep_wf1t(const float* __restrict__ Wf1,
                                                 float* __restrict__ wf1t) {
    const int i = blockIdx.x * 256 + threadIdx.x;   // 294912 total
    const int k = i % 1152, h = i / 1152;
    wf1t[i] = Wf1[k * 256 + h];
}

// ---------------------------------------------------------------------------
// Stage x_t into T1 channels [0,11), transposed padded layout (stride 96)
// ---------------------------------------------------------------------------
__global__ __launch_bounds__(256) void stage_x(const float* __restrict__ X,
                                               _Float16* __restrict__ T1, int t) {
    int i = blockIdx.x * 256 + threadIdx.x;   // 2*1024*16
    const int c = i & 15;
    const int pix = (i >> 4) & 1023;
    const int b = i >> 14;
    if (c >= 11 || b >= NB) return;
    const int y = pix >> 5, x = pix & 31;
    const int pp = (y + 2) * PADW + (x + 2);
    T1[((size_t)(b * PPLANE) + pp) * 96 + c] =
        (_Float16)X[(((b * TX + t) * 11 + c) << 10) + pix];
}

// ---------------------------------------------------------------------------
// MFMA ConvLSTM cell v6: r10 change = N-split for occupancy.
// Block: 64m x 32n (ONE pixel row), 4 waves (2wm x 2wn), wave 32m x 16n,
// acc 2x1. grid = NM * 64 -> 512 blocks for cells2/3 = 2 blocks/CU = 2
// waves/SIMD (TLP hides barrier drain + A-ring exposure; was 1 wave/SIMD).
// LDS slab: 5 rows x 4 c8 x 36 cols = 720 slots (pad 768) x 16B, 2 buffers.
// slot = (rr*4 + c8)*36 + col; DMA staging linear, decode = layout inverse.
// A pipeline: depth PDA=5 (25%5==0 keeps ring aligned across chunks).
// B pipeline: depth 3, re-prologued per chunk.
// mtile = bid % NM -> XCD round-robin keeps weights L2-local.
// ---------------------------------------------------------------------------
template <int CTOTP, int CH, int NM>
__global__ __launch_bounds__(256, 2) void cell_mfma6(
    const _Float16* __restrict__ T,      // (2, 1296, CTOTP)
    const _Float16* __restrict__ Wk,     // chunked layout, see prep_w2
    const float* __restrict__ Bias,     // (4CH) gate-block layout
    float* __restrict__ Cst,            // (2, CH, 1024) fp32, in/out
    _Float16* __restrict__ outA, int strideA,   // pre-offset by channel base
    _Float16* __restrict__ outB, int strideB,   // optional
    float* __restrict__ outP)                   // optional plain (2,CH,1024)
{
    constexpr int M = 4 * CH;
    constexpr int NCH = CTOTP / 32;
    constexpr int PDA = 5;              // A prefetch depth; must divide 25
    // 2 buffers x 768 slots x 16B = 24576 B (720 real slots + 48 pad)
    __shared__ _Float16 slab[2 * 768 * 8];

    const int tid = threadIdx.x;
    const int wave = tid >> 6, lane = tid & 63;
    const int l16 = lane & 15, lk = lane >> 4;
    const int wm = wave >> 1, wn = wave & 1;
    const int bid = blockIdx.x;
    const int mtile = bid % NM;            // 64-row m tile
    const int ntile = bid / NM;            // 32-pixel n tile
    const int nbase = ntile * 32;
    const int b = nbase >> 10;
    const int y0 = (nbase & 1023) >> 5;    // the single pixel row
    const _Float16* Tb = T + (size_t)(b * PPLANE) * CTOTP;

    f32x4 acc[2] = {};

    // B base byte offset: slab[(dy*4+lk)*36 + x+dx] -> bbase + (dy*144+dx)*16
    const int pxl = wn * 16 + l16;         // 0..31 within row
    const int bbase = (lk * 36 + pxl) * 16;
    const int laneAoff = lk * 128 + l16 * 8;   // element offset within 512-frag

    // A-fragment load: chunk cc (runtime), tap dd (static), mt (static)
    auto loadA = [&](int cc, int dd, int mt) -> half8 {
        const int mb = mtile * 4 + wm * 2 + mt;
        return *(const half8*)(Wk +
            (size_t)(((dd * (M / 16) + mb) * NCH + cc) * 512 + laneAoff));
    };

    // Stage chunk c32 into buf[c32&1]: 12 wave-segments of 64 linear slots.
    // Decode inverts slot = (rr*4+c8)*36 + col. Pad slots (rc>=20) read row
    // y0+5 (<=36, stays inside d_ws arena) and are never read from LDS.
    auto stage = [&](int c32) {
        char* dst = (char*)slab + (c32 & 1) * 12288;
#pragma unroll
        for (int k = 0; k < 3; ++k) {
            const int s = wave + k * 4;    // 0..11
            const int idx = (s << 6) + lane;
            const int col = idx % 36;
            const int rc  = idx / 36;
            const int c8 = rc & 3, rr = rc >> 2;
            const _Float16* src = Tb +
                (size_t)((y0 + rr) * PADW + col) * CTOTP + c32 * 32 + c8 * 8;
            gload_lds16(src, dst + idx * 16);
        }
    };

    // A pipeline prologue: taps 0..PDA-1 of chunk 0
    half8 apre[PDA][2];
#pragma unroll
    for (int p = 0; p < PDA; ++p) {
        apre[p][0] = loadA(0, p, 0);
        apre[p][1] = loadA(0, p, 1);
    }

    stage(0);
    __syncthreads();                        // drains DMA before first compute

    for (int c32 = 0; c32 < NCH; ++c32) {
        if (c32 + 1 < NCH) stage(c32 + 1);  // async DMA into other buffer
        const char* sb = (const char*)slab + (c32 & 1) * 12288;

        // B pipeline prologue: taps 0..2 of this chunk
        half8 bpre[3];
#pragma unroll
        for (int p = 0; p < 3; ++p)
            bpre[p] = *(const half8*)(sb + bbase + ((p / 5) * 144 + (p % 5)) * 16);

#pragma unroll
        for (int d = 0; d < 25; ++d) {
            const half8 a0 = apre[d % PDA][0];
            const half8 a1 = apre[d % PDA][1];
            const half8 b0 = bpre[d % 3];

            // refill A slot with tap d+PDA (same ring slot; crosses chunks)
            {
                const int dp = d + PDA;
                const int cstep = dp / 25;          // 0 or 1 (static)
                const int dd = dp % 25;             // static
                if (cstep == 0 || c32 + 1 < NCH) {
                    const int cc = c32 + cstep;
                    apre[d % PDA][0] = loadA(cc, dd, 0);
                    apre[d % PDA][1] = loadA(cc, dd, 1);
                }
            }
            // refill B slot with tap d+3 (within chunk)
            if (d + 3 < 25) {
                const int dy = (d + 3) / 5, dx = (d + 3) % 5;
                bpre[d % 3] = *(const half8*)(sb + bbase + (dy * 144 + dx) * 16);
            }

            acc[0] = __builtin_amdgcn_mfma_f32_16x16x32_f16(a0, b0, acc[0], 0, 0, 0);
            acc[1] = __builtin_amdgcn_mfma_f32_16x16x32_f16(a1, b0, acc[1], 0, 0, 0);
        }
        __syncthreads();   // waits compute ds_reads AND in-flight DMA/prefetch
    }

    // Epilogue: lane-local LSTM update. D row = lk*4 + r -> gates i,f,o,g.
    const int pix = (nbase & 1023) + pxl;
    const int x = pix & 31;
    const size_t pp = (size_t)(b * PPLANE) + (y0 + 2) * PADW + (x + 2);
#pragma unroll
    for (int mt = 0; mt < 2; ++mt) {
        const int hc = mtile * 16 + wm * 8 + mt * 4 + lk;
        const f32x4 a = acc[mt];
        const float gi = a[0] + Bias[hc];
        const float gf = a[1] + Bias[CH + hc];
        const float go = a[2] + Bias[2 * CH + hc];
        const float gg = a[3] + Bias[3 * CH + hc];
        const int idx = ((b * CH + hc) << 10) + pix;
        const float c_old = Cst[idx];
        const float cn = sigf(gf) * c_old + sigf(gi) * tanhf(gg);
        const float hn = sigf(go) * tanhf(cn);
        Cst[idx] = cn;
        const _Float16 hh = (_Float16)hn;
        outA[pp * strideA + hc] = hh;
        if (outB) outB[pp * strideB + hc] = hh;
        if (outP) outP[idx] = hn;
    }
}

// ---------------------------------------------------------------------------
// head kernel: fused meo (1x1 conv) + aqi (patch MLP) + stage_x(t+1).
// grid (99, NB): bx<35 aqi station; 35<=bx<55 meo; bx>=55 staging.
// Staging writes T1[nxt] ch0..10 — disjoint from cell1(t)'s ch11+ h-writes.
// aqi layer1 uses transposed wf1t: per-thread contiguous f32x4 weight loads
// (288 b128 vs 1152 scalar b32 in r10), 16 independent FMA chains.
// ---------------------------------------------------------------------------
__global__ __launch_bounds__(256) void head_kernel(
    const float* __restrict__ H3, const float* __restrict__ Wm,
    const float* __restrict__ bm, const float* __restrict__ wf1t,
    const float* __restrict__ bf1, const float* __restrict__ Wf2,
    const float* __restrict__ bf2, const int* __restrict__ locs,
    const float* __restrict__ X, _Float16* __restrict__ T1nxt,
    float* __restrict__ out, int t) {
    const int bx = blockIdx.x, b = blockIdx.y, tid = threadIdx.x;
    if (bx >= 55) {            // stage x(t+1)
        if (t + 1 < TX) {
            const int idx = (bx - 55) * 256 + tid;      // 0..11263
            const int c = idx >> 10, pix = idx & 1023;
            const int y = pix >> 5, x = pix & 31;
            T1nxt[((size_t)(b * PPLANE) + (y + 2) * PADW + (x + 2)) * 96 + c] =
                (_Float16)X[(((b * TX + t + 1) * 11 + c) << 10) + pix];
        }
        return;
    }
    if (bx >= NSTA) {          // meo: 20 blocks per b
        const int idx = (bx - NSTA) * 256 + tid;        // 0..5119
        const int oc = idx >> 10, pix = idx & 1023;
        const float* w = Wm + oc * 128;
        const float* h = H3 + ((b * 128) << 10) + pix;
        float a0 = 0.f, a1 = 0.f, a2 = 0.f, a3 = 0.f;
#pragma unroll
        for (int c = 0; c < 128; c += 4) {
            a0 = fmaf(w[c],     h[c << 10],       a0);
            a1 = fmaf(w[c + 1], h[(c + 1) << 10], a1);
            a2 = fmaf(w[c + 2], h[(c + 2) << 10], a2);
            a3 = fmaf(w[c + 3], h[(c + 3) << 10], a3);
        }
        out[2520 + (b * TX + t) * 5120 + idx] = ((a0 + a1) + (a2 + a3)) + bm[oc];
        return;
    }
    // aqi station s = bx
    __shared__ float feats[1152];
    __shared__ float hid[256];
    const int s = bx;
    const int y0 = locs[2 * s], x0 = locs[2 * s + 1];
    for (int k = tid; k < 1152; k += 256) {
        const int c = k / 9, r = k % 9;
        feats[k] = H3[((b * 128 + c) << 10) + (y0 + r / 3) * 32 + (x0 + r % 3)];
    }
    __syncthreads();
    {
        f32x4 a[4] = {};
        const f32x4* wr = (const f32x4*)(wf1t + (size_t)tid * 1152);
        const f32x4* fr = (const f32x4*)feats;
#pragma unroll
        for (int kk = 0; kk < 288; kk += 4) {
#pragma unroll
            for (int u = 0; u < 4; ++u) a[u] += wr[kk + u] * fr[kk + u];
        }
        const f32x4 sv = (a[0] + a[1]) + (a[2] + a[3]);
        hid[tid] = tanhf(sv[0] + sv[1] + sv[2] + sv[3] + bf1[tid]);
    }
    __syncthreads();
    if (tid < 6) {
        float ac[8] = {};
#pragma unroll
        for (int k = 0; k < 256; k += 8) {
#pragma unroll
            for (int u = 0; u < 8; ++u)
                ac[u] = fmaf(hid[k + u], Wf2[(k + u) * 6 + tid], ac[u]);
        }
        out[(b * TX + t) * 210 + s * 6 + tid] =
            ((ac[0] + ac[1]) + (ac[2] + ac[3])) +
            ((ac[4] + ac[5]) + (ac[6] + ac[7])) + bf2[tid];
    }
}

// ---------------------------------------------------------------------------
extern "C" void kernel_launch(void* const* d_in, const int* in_sizes, int n_in,
                              void* d_out, int out_size, void* d_ws, size_t ws_size,
                              hipStream_t stream) {
    const float* X   = (const float*)d_in[0];
    const float* W1  = (const float*)d_in[1];
    const float* b1  = (const float*)d_in[2];
    const float* W2  = (const float*)d_in[3];
    const float* b2  = (const float*)d_in[4];
    const float* W3  = (const float*)d_in[5];
    const float* b3  = (const float*)d_in[6];
    const float* Wm  = (const float*)d_in[7];
    const float* bm  = (const float*)d_in[8];
    const float* Wf1 = (const float*)d_in[9];
    const float* bf1 = (const float*)d_in[10];
    const float* Wf2 = (const float*)d_in[11];
    const float* bf2 = (const float*)d_in[12];
    const int* locs  = (const int*)d_in[13];
    float* out = (float*)d_out;

    // Byte-offset allocator, 256B aligned
    char* base = (char*)d_ws;
    size_t off = 0;
    auto alloc = [&](size_t bytes) -> char* {
        char* p = base + off;
        off = (off + bytes + 255) & ~(size_t)255;
        return p;
    };
    // Zeroed region: T buffers (f16), C states (fp32), H3
    _Float16* T1[2]; T1[0] = (_Float16*)alloc(2 * PPLANE * 96 * 2);
                     T1[1] = (_Float16*)alloc(2 * PPLANE * 96 * 2);
    _Float16* T2[2]; T2[0] = (_Float16*)alloc(2 * PPLANE * 192 * 2);
                     T2[1] = (_Float16*)alloc(2 * PPLANE * 192 * 2);
    _Float16* T3[2]; T3[0] = (_Float16*)alloc(2 * PPLANE * 256 * 2);
                     T3[1] = (_Float16*)alloc(2 * PPLANE * 256 * 2);
    float* C1 = (float*)alloc(2 * 64 * 1024 * 4);
    float* C2 = (float*)alloc(2 * 128 * 1024 * 4);
    float* C3 = (float*)alloc(2 * 128 * 1024 * 4);
    float* H3 = (float*)alloc(2 * 128 * 1024 * 4);
    const size_t zero_bytes = off;
    // Non-zeroed: fully written by prep each call
    _Float16* Wk1 = (_Float16*)alloc((size_t)25 * 256 * 96 * 2);
    _Float16* Wk2 = (_Float16*)alloc((size_t)25 * 512 * 192 * 2);
    _Float16* Wk3 = (_Float16*)alloc((size_t)25 * 512 * 256 * 2);
    float* wf1t = (float*)alloc((size_t)256 * 1152 * 4);

    hipMemsetAsync(d_ws, 0, zero_bytes, stream);

    prep_w2<75, 96, 64><<<dim3((25 * 256 * 96 + 255) / 256), 256, 0, stream>>>(W1, Wk1);
    prep_w2<192, 192, 128><<<dim3((25 * 512 * 192 + 255) / 256), 256, 0, stream>>>(W2, Wk2);
    prep_w2<256, 256, 128><<<dim3((25 * 512 * 256 + 255) / 256), 256, 0, stream>>>(W3, Wk3);
    prep_wf1t<<<dim3(1152), 256, 0, stream>>>(Wf1, wf1t);

    stage_x<<<dim3(128), 256, 0, stream>>>(X, T1[0], 0);

    for (int t = 0; t < TX; ++t) {
        const int cur = t & 1, nxt = cur ^ 1;
        // cell1: T1[cur](96) -> h1 to T1[nxt]@11 and T2[cur]@0   (M=256 -> NM=4)
        cell_mfma6<96, 64, 4><<<dim3(4 * 64), 256, 0, stream>>>(
            T1[cur], Wk1, b1, C1, T1[nxt] + 11, 96, T2[cur] + 0, 192, nullptr);
        // cell2: T2[cur](192) -> h2 to T2[nxt]@64 and T3[cur]@0  (M=512 -> NM=8)
        cell_mfma6<192, 128, 8><<<dim3(8 * 64), 256, 0, stream>>>(
            T2[cur], Wk2, b2, C2, T2[nxt] + 64, 192, T3[cur] + 0, 256, nullptr);
        // cell3: T3[cur](256) -> h3 to T3[nxt]@128 and plain H3
        cell_mfma6<256, 128, 8><<<dim3(8 * 64), 256, 0, stream>>>(
            T3[cur], Wk3, b3, C3, T3[nxt] + 128, 256, nullptr, 0, H3);
        // heads for t + stage x(t+1) into T1[nxt] (ch 0..10, no race w/ cell1)
        head_kernel<<<dim3(99, NB), 256, 0, stream>>>(
            H3, Wm, bm, wf1t, bf1, Wf2, bf2, locs, X, T1[nxt], out, t);
    }
}

// Round 12
// 544.523 us; speedup vs baseline: 1.3656x; 1.3656x over previous
//
#include <hip/hip_runtime.h>
#include <math.h>

// Problem constants
#define TX 6
#define NB 2
#define NSTA 35
#define PPLANE 1296      // 36*36 padded plane
#define PADW 36

typedef __attribute__((ext_vector_type(8))) _Float16 half8;
typedef __attribute__((ext_vector_type(4))) float f32x4;

__device__ __forceinline__ float sigf(float x) { return 1.0f / (1.0f + __expf(-x)); }

// Async global->LDS DMA, 16B per lane. LDS dest is wave-uniform base + lane*16.
__device__ __forceinline__ void gload_lds16(const void* g, void* l) {
    __builtin_amdgcn_global_load_lds(
        (const __attribute__((address_space(1))) void*)g,
        (__attribute__((address_space(3))) void*)l, 16, 0, 0);
}

// ---------------------------------------------------------------------------
// Weight prep: W (4CH,CTOT,5,5) fp32 gate-block-major ->
// Wk[d][mb][c32][lk][l16][e8] f16 : fragment = 512 f16 (16 m-rows x 32 cin).
// ---------------------------------------------------------------------------
template <int CTOT, int CTOTP, int CH>
__global__ __launch_bounds__(256) void prep_w2(const float* __restrict__ W,
                                               _Float16* __restrict__ Wk) {
    constexpr int M = 4 * CH;
    const int total = 25 * M * CTOTP;
    int i = blockIdx.x * 256 + threadIdx.x;
    if (i >= total) return;
    const int e   = i & 7;
    const int l16 = (i >> 3) & 15;
    const int lk  = (i >> 7) & 3;
    const int c32 = (i >> 9) % (CTOTP / 32);
    const int rest = (i >> 9) / (CTOTP / 32);
    const int mb = rest % (M / 16);
    const int d  = rest / (M / 16);
    const int m = mb * 16 + l16;
    const int cin = c32 * 32 + lk * 8 + e;
    const int hc = m >> 2, g = m & 3;
    float v = 0.f;
    if (cin < CTOT) v = W[((g * CH + hc) * CTOT + cin) * 25 + d];
    Wk[i] = (_Float16)v;
}

// ---------------------------------------------------------------------------
// Stage x_t into T1 channels [0,11), transposed padded layout (stride 96)
// ---------------------------------------------------------------------------
__global__ __launch_bounds__(256) void stage_x(const float* __restrict__ X,
                                               _Float16* __restrict__ T1, int t) {
    int i = blockIdx.x * 256 + threadIdx.x;   // 2*1024*16
    const int c = i & 15;
    const int pix = (i >> 4) & 1023;
    const int b = i >> 14;
    if (c >= 11 || b >= NB) return;
    const int y = pix >> 5, x = pix & 31;
    const int pp = (y + 2) * PADW + (x + 2);
    T1[((size_t)(b * PPLANE) + pp) * 96 + c] =
        (_Float16)X[(((b * TX + t) * 11 + c) << 10) + pix];
}

// ---------------------------------------------------------------------------
// MFMA ConvLSTM cell v5 (r9/r10 measured-best config, reverted from r11's
// N-split which regressed): DMA-staged B (double-buffered) + register
// software-pipelined A (depth PDA=5, 25%5==0 keeps ring aligned across chunk
// boundaries) and B (depth 3, re-prologued per chunk).
// GEMM: gates[M][N], M = 4*CH (m = hc*4+gate), N = 2048, K = 25*CTOTP.
// Block: 64m x 64n, 4 waves (2wm x 2wn), wave 32x32, acc 2x2.
// LDS slab (16B slots): slot = (rr*4 + c8)*36 + col; DMA decode = inverse.
// grid = NM * 32; mtile = bid % NM -> XCD round-robin keeps weights L2-local.
// ---------------------------------------------------------------------------
template <int CTOTP, int CH, int NM>
__global__ __launch_bounds__(256) void cell_mfma5(
    const _Float16* __restrict__ T,      // (2, 1296, CTOTP)
    const _Float16* __restrict__ Wk,     // chunked layout, see prep_w2
    const float* __restrict__ Bias,     // (4CH) gate-block layout
    float* __restrict__ Cst,            // (2, CH, 1024) fp32, in/out
    _Float16* __restrict__ outA, int strideA,   // pre-offset by channel base
    _Float16* __restrict__ outB, int strideB,   // optional
    float* __restrict__ outP)                   // optional plain (2,CH,1024)
{
    constexpr int M = 4 * CH;
    constexpr int NCH = CTOTP / 32;
    constexpr int PDA = 5;              // A prefetch depth; must divide 25
    // 2 buffers x 896 slots x 16B = 28672 B (864 real slots + 32 pad)
    __shared__ _Float16 slab[2 * 896 * 8];

    const int tid = threadIdx.x;
    const int wave = tid >> 6, lane = tid & 63;
    const int l16 = lane & 15, lk = lane >> 4;
    const int wm = wave >> 1, wn = wave & 1;
    const int bid = blockIdx.x;
    const int mtile = bid % NM;            // 64-row m tile
    const int ntile = bid / NM;            // 64-pixel n tile
    const int nbase = ntile * 64;
    const int b = nbase >> 10;
    const int y0 = (nbase & 1023) >> 5;    // first pixel row (even)
    const _Float16* Tb = T + (size_t)(b * PPLANE) * CTOTP;

    f32x4 acc[2][2] = {};

    // B base byte offsets: slab[r+dy][lk][x+dx] -> bbase + (dy*144+dx)*16
    int bbase[2];
#pragma unroll
    for (int nt = 0; nt < 2; ++nt) {
        const int pxl = wn * 32 + nt * 16 + l16;
        const int r = pxl >> 5, x = pxl & 31;
        bbase[nt] = (((r * 4 + lk) * 36) + x) * 16;
    }
    const int laneAoff = lk * 128 + l16 * 8;   // element offset within 512-frag

    // A-fragment load: chunk cc (runtime), tap dd (static), mt (static)
    auto loadA = [&](int cc, int dd, int mt) -> half8 {
        const int mb = mtile * 4 + wm * 2 + mt;
        return *(const half8*)(Wk +
            (size_t)(((dd * (M / 16) + mb) * NCH + cc) * 512 + laneAoff));
    };

    // Stage chunk c32 into buf[c32&1]: linear slot idx; decode inverts
    // slot = (rr*4+c8)*36 + col  (r6 bugfix decode).
    auto stage = [&](int c32) {
        char* dst = (char*)slab + (c32 & 1) * 14336;
#pragma unroll
        for (int k = 0; k < 4; ++k) {
            const int s = wave + k * 4;
            if (s < 14) {
                const int idx = (s << 6) + lane;
                const int col = idx % 36;
                const int rc  = idx / 36;          // rr*4 + c8 (rc=24: pad, unread)
                const int c8 = rc & 3, rr = rc >> 2;
                const _Float16* src = Tb +
                    (size_t)((y0 + rr) * PADW + col) * CTOTP + c32 * 32 + c8 * 8;
                gload_lds16(src, dst + idx * 16);
            }
        }
    };

    // A pipeline prologue: taps 0..PDA-1 of chunk 0
    half8 apre[PDA][2];
#pragma unroll
    for (int p = 0; p < PDA; ++p) {
        apre[p][0] = loadA(0, p, 0);
        apre[p][1] = loadA(0, p, 1);
    }

    stage(0);
    __syncthreads();                        // drains DMA before first compute

    for (int c32 = 0; c32 < NCH; ++c32) {
        if (c32 + 1 < NCH) stage(c32 + 1);  // async DMA into other buffer
        const char* sb = (const char*)slab + (c32 & 1) * 14336;

        // B pipeline prologue: taps 0..2 of this chunk
        half8 bpre[3][2];
#pragma unroll
        for (int p = 0; p < 3; ++p) {
            const int dy = p / 5, dx = p % 5;
            bpre[p][0] = *(const half8*)(sb + bbase[0] + (dy * 144 + dx) * 16);
            bpre[p][1] = *(const half8*)(sb + bbase[1] + (dy * 144 + dx) * 16);
        }

#pragma unroll
        for (int d = 0; d < 25; ++d) {
            const half8 a0 = apre[d % PDA][0];
            const half8 a1 = apre[d % PDA][1];
            const half8 b0 = bpre[d % 3][0];
            const half8 b1 = bpre[d % 3][1];

            // refill A slot with tap d+PDA (same ring slot; crosses chunks)
            {
                const int dp = d + PDA;
                const int cstep = dp / 25;          // 0 or 1 (static)
                const int dd = dp % 25;             // static
                if (cstep == 0 || c32 + 1 < NCH) {
                    const int cc = c32 + cstep;
                    apre[d % PDA][0] = loadA(cc, dd, 0);
                    apre[d % PDA][1] = loadA(cc, dd, 1);
                }
            }
            // refill B slot with tap d+3 (within chunk)
            if (d + 3 < 25) {
                const int dy = (d + 3) / 5, dx = (d + 3) % 5;
                bpre[d % 3][0] = *(const half8*)(sb + bbase[0] + (dy * 144 + dx) * 16);
                bpre[d % 3][1] = *(const half8*)(sb + bbase[1] + (dy * 144 + dx) * 16);
            }

            acc[0][0] = __builtin_amdgcn_mfma_f32_16x16x32_f16(a0, b0, acc[0][0], 0, 0, 0);
            acc[0][1] = __builtin_amdgcn_mfma_f32_16x16x32_f16(a0, b1, acc[0][1], 0, 0, 0);
            acc[1][0] = __builtin_amdgcn_mfma_f32_16x16x32_f16(a1, b0, acc[1][0], 0, 0, 0);
            acc[1][1] = __builtin_amdgcn_mfma_f32_16x16x32_f16(a1, b1, acc[1][1], 0, 0, 0);
        }
        __syncthreads();   // waits compute ds_reads AND in-flight DMA/prefetch
    }

    // Epilogue: lane-local LSTM update. D row = lk*4 + r -> gates i,f,o,g.
#pragma unroll
    for (int mt = 0; mt < 2; ++mt) {
        const int hc = mtile * 16 + wm * 8 + mt * 4 + lk;
        const float bi = Bias[hc], bf = Bias[CH + hc];
        const float bo = Bias[2 * CH + hc], bg = Bias[3 * CH + hc];
#pragma unroll
        for (int nt = 0; nt < 2; ++nt) {
            const int pxl = wn * 32 + nt * 16 + l16;
            const int pix = (nbase & 1023) + pxl;
            const int y = pix >> 5, x = pix & 31;
            const f32x4 a = acc[mt][nt];
            const float gi = a[0] + bi, gf = a[1] + bf;
            const float go = a[2] + bo, gg = a[3] + bg;
            const int idx = ((b * CH + hc) << 10) + pix;
            const float c_old = Cst[idx];
            const float cn = sigf(gf) * c_old + sigf(gi) * tanhf(gg);
            const float hn = sigf(go) * tanhf(cn);
            Cst[idx] = cn;
            const _Float16 hh = (_Float16)hn;
            const size_t pp = (size_t)(b * PPLANE) + (y + 2) * PADW + (x + 2);
            outA[pp * strideA + hc] = hh;
            if (outB) outB[pp * strideB + hc] = hh;
            if (outP) outP[idx] = hn;
        }
    }
}

// ---------------------------------------------------------------------------
// head kernel v2 (512 threads): fused meo + aqi + stage_x(t+1).
// grid (67, NB): bx<35 aqi; 35<=bx<45 meo; bx>=45 staging.
// aqi r12 fix: COALESCED Wf1[k*256+h] (r11 transpose broke inter-lane
// coalescing: lanes 4.6KB apart, 64 lines/instr). Latency hidden by 2-way
// k-split (waves 0-3: k<576 for h=tid&255; waves 4-7: k>=576) x 16
// accumulators = 32 independent loads in flight per h (r10 had 8).
// LDS partial-sum reduce, then layer 2 as before.
// ---------------------------------------------------------------------------
__global__ __launch_bounds__(512) void head_kernel(
    const float* __restrict__ H3, const float* __restrict__ Wm,
    const float* __restrict__ bm, const float* __restrict__ Wf1,
    const float* __restrict__ bf1, const float* __restrict__ Wf2,
    const float* __restrict__ bf2, const int* __restrict__ locs,
    const float* __restrict__ X, _Float16* __restrict__ T1nxt,
    float* __restrict__ out, int t) {
    const int bx = blockIdx.x, b = blockIdx.y, tid = threadIdx.x;
    if (bx >= 45) {            // stage x(t+1): 22 blocks, 11264 elems
        if (t + 1 < TX) {
            const int idx = (bx - 45) * 512 + tid;
            const int c = idx >> 10, pix = idx & 1023;
            const int y = pix >> 5, x = pix & 31;
            T1nxt[((size_t)(b * PPLANE) + (y + 2) * PADW + (x + 2)) * 96 + c] =
                (_Float16)X[(((b * TX + t + 1) * 11 + c) << 10) + pix];
        }
        return;
    }
    if (bx >= NSTA) {          // meo: 10 blocks, 5120 elems
        const int idx = (bx - NSTA) * 512 + tid;
        const int oc = idx >> 10, pix = idx & 1023;
        const float* w = Wm + oc * 128;
        const float* h = H3 + ((b * 128) << 10) + pix;
        float a0 = 0.f, a1 = 0.f, a2 = 0.f, a3 = 0.f;
#pragma unroll
        for (int c = 0; c < 128; c += 4) {
            a0 = fmaf(w[c],     h[c << 10],       a0);
            a1 = fmaf(w[c + 1], h[(c + 1) << 10], a1);
            a2 = fmaf(w[c + 2], h[(c + 2) << 10], a2);
            a3 = fmaf(w[c + 3], h[(c + 3) << 10], a3);
        }
        out[2520 + (b * TX + t) * 5120 + idx] = ((a0 + a1) + (a2 + a3)) + bm[oc];
        return;
    }
    // aqi station s = bx
    __shared__ float feats[1152];
    __shared__ float psum[2][256];
    __shared__ float hid[256];
    const int s = bx;
    const int y0 = locs[2 * s], x0 = locs[2 * s + 1];
    for (int k = tid; k < 1152; k += 512) {
        const int c = k / 9, r = k % 9;
        feats[k] = H3[((b * 128 + c) << 10) + (y0 + r / 3) * 32 + (x0 + r % 3)];
    }
    __syncthreads();
    {
        const int h = tid & 255, kh = tid >> 8;
        const int kb = kh * 576;
        float ac[16] = {};
        for (int kk = 0; kk < 576; kk += 16) {
#pragma unroll
            for (int u = 0; u < 16; ++u)
                ac[u] = fmaf(feats[kb + kk + u], Wf1[(kb + kk + u) * 256 + h], ac[u]);
        }
        psum[kh][h] = (((ac[0] + ac[1]) + (ac[2] + ac[3])) +
                       ((ac[4] + ac[5]) + (ac[6] + ac[7]))) +
                      (((ac[8] + ac[9]) + (ac[10] + ac[11])) +
                       ((ac[12] + ac[13]) + (ac[14] + ac[15])));
    }
    __syncthreads();
    if (tid < 256) hid[tid] = tanhf(psum[0][tid] + psum[1][tid] + bf1[tid]);
    __syncthreads();
    if (tid < 6) {
        float ac[8] = {};
#pragma unroll
        for (int k = 0; k < 256; k += 8) {
#pragma unroll
            for (int u = 0; u < 8; ++u)
                ac[u] = fmaf(hid[k + u], Wf2[(k + u) * 6 + tid], ac[u]);
        }
        out[(b * TX + t) * 210 + s * 6 + tid] =
            ((ac[0] + ac[1]) + (ac[2] + ac[3])) +
            ((ac[4] + ac[5]) + (ac[6] + ac[7])) + bf2[tid];
    }
}

// ---------------------------------------------------------------------------
extern "C" void kernel_launch(void* const* d_in, const int* in_sizes, int n_in,
                              void* d_out, int out_size, void* d_ws, size_t ws_size,
                              hipStream_t stream) {
    const float* X   = (const float*)d_in[0];
    const float* W1  = (const float*)d_in[1];
    const float* b1  = (const float*)d_in[2];
    const float* W2  = (const float*)d_in[3];
    const float* b2  = (const float*)d_in[4];
    const float* W3  = (const float*)d_in[5];
    const float* b3  = (const float*)d_in[6];
    const float* Wm  = (const float*)d_in[7];
    const float* bm  = (const float*)d_in[8];
    const float* Wf1 = (const float*)d_in[9];
    const float* bf1 = (const float*)d_in[10];
    const float* Wf2 = (const float*)d_in[11];
    const float* bf2 = (const float*)d_in[12];
    const int* locs  = (const int*)d_in[13];
    float* out = (float*)d_out;

    // Byte-offset allocator, 256B aligned
    char* base = (char*)d_ws;
    size_t off = 0;
    auto alloc = [&](size_t bytes) -> char* {
        char* p = base + off;
        off = (off + bytes + 255) & ~(size_t)255;
        return p;
    };
    // Zeroed region: T buffers (f16), C states (fp32), H3
    _Float16* T1[2]; T1[0] = (_Float16*)alloc(2 * PPLANE * 96 * 2);
                     T1[1] = (_Float16*)alloc(2 * PPLANE * 96 * 2);
    _Float16* T2[2]; T2[0] = (_Float16*)alloc(2 * PPLANE * 192 * 2);
                     T2[1] = (_Float16*)alloc(2 * PPLANE * 192 * 2);
    _Float16* T3[2]; T3[0] = (_Float16*)alloc(2 * PPLANE * 256 * 2);
                     T3[1] = (_Float16*)alloc(2 * PPLANE * 256 * 2);
    float* C1 = (float*)alloc(2 * 64 * 1024 * 4);
    float* C2 = (float*)alloc(2 * 128 * 1024 * 4);
    float* C3 = (float*)alloc(2 * 128 * 1024 * 4);
    float* H3 = (float*)alloc(2 * 128 * 1024 * 4);
    const size_t zero_bytes = off;
    // Non-zeroed: fully written by prep each call
    _Float16* Wk1 = (_Float16*)alloc((size_t)25 * 256 * 96 * 2);
    _Float16* Wk2 = (_Float16*)alloc((size_t)25 * 512 * 192 * 2);
    _Float16* Wk3 = (_Float16*)alloc((size_t)25 * 512 * 256 * 2);

    hipMemsetAsync(d_ws, 0, zero_bytes, stream);

    prep_w2<75, 96, 64><<<dim3((25 * 256 * 96 + 255) / 256), 256, 0, stream>>>(W1, Wk1);
    prep_w2<192, 192, 128><<<dim3((25 * 512 * 192 + 255) / 256), 256, 0, stream>>>(W2, Wk2);
    prep_w2<256, 256, 128><<<dim3((25 * 512 * 256 + 255) / 256), 256, 0, stream>>>(W3, Wk3);

    stage_x<<<dim3(128), 256, 0, stream>>>(X, T1[0], 0);

    for (int t = 0; t < TX; ++t) {
        const int cur = t & 1, nxt = cur ^ 1;
        // cell1: T1[cur](96) -> h1 to T1[nxt]@11 and T2[cur]@0   (M=256 -> NM=4)
        cell_mfma5<96, 64, 4><<<dim3(4 * 32), 256, 0, stream>>>(
            T1[cur], Wk1, b1, C1, T1[nxt] + 11, 96, T2[cur] + 0, 192, nullptr);
        // cell2: T2[cur](192) -> h2 to T2[nxt]@64 and T3[cur]@0  (M=512 -> NM=8)
        cell_mfma5<192, 128, 8><<<dim3(8 * 32), 256, 0, stream>>>(
            T2[cur], Wk2, b2, C2, T2[nxt] + 64, 192, T3[cur] + 0, 256, nullptr);
        // cell3: T3[cur](256) -> h3 to T3[nxt]@128 and plain H3
        cell_mfma5<256, 128, 8><<<dim3(8 * 32), 256, 0, stream>>>(
            T3[cur], Wk3, b3, C3, T3[nxt] + 128, 256, nullptr, 0, H3);
        // heads for t + stage x(t+1) into T1[nxt] (ch 0..10, no race w/ cell1)
        head_kernel<<<dim3(67, NB), 512, 0, stream>>>(
            H3, Wm, bm, Wf1, bf1, Wf2, bf2, locs, X, T1[nxt], out, t);
    }
}

// Round 13
// 492.066 us; speedup vs baseline: 1.5112x; 1.1066x over previous
//
#include <hip/hip_runtime.h>
#include <math.h>

// Problem constants
#define TX 6
#define NB 2
#define NSTA 35
#define PPLANE 1296      // 36*36 padded plane
#define PADW 36

typedef __attribute__((ext_vector_type(8))) _Float16 half8;
typedef __attribute__((ext_vector_type(4))) float f32x4;

__device__ __forceinline__ float sigf(float x) { return 1.0f / (1.0f + __expf(-x)); }

// Async global->LDS DMA, 16B per lane. LDS dest is wave-uniform base + lane*16.
__device__ __forceinline__ void gload_lds16(const void* g, void* l) {
    __builtin_amdgcn_global_load_lds(
        (const __attribute__((address_space(1))) void*)g,
        (__attribute__((address_space(3))) void*)l, 16, 0, 0);
}

// ---------------------------------------------------------------------------
// Weight prep: W (4CH,CTOT,5,5) fp32 gate-block-major ->
// Wk[d][mb][c32][lk][l16][e8] f16 : fragment = 512 f16 (16 m-rows x 32 cin).
// ---------------------------------------------------------------------------
template <int CTOT, int CTOTP, int CH>
__global__ __launch_bounds__(256) void prep_w2(const float* __restrict__ W,
                                               _Float16* __restrict__ Wk) {
    constexpr int M = 4 * CH;
    const int total = 25 * M * CTOTP;
    int i = blockIdx.x * 256 + threadIdx.x;
    if (i >= total) return;
    const int e   = i & 7;
    const int l16 = (i >> 3) & 15;
    const int lk  = (i >> 7) & 3;
    const int c32 = (i >> 9) % (CTOTP / 32);
    const int rest = (i >> 9) / (CTOTP / 32);
    const int mb = rest % (M / 16);
    const int d  = rest / (M / 16);
    const int m = mb * 16 + l16;
    const int cin = c32 * 32 + lk * 8 + e;
    const int hc = m >> 2, g = m & 3;
    float v = 0.f;
    if (cin < CTOT) v = W[((g * CH + hc) * CTOT + cin) * 25 + d];
    Wk[i] = (_Float16)v;
}

// ---------------------------------------------------------------------------
// Stage x_t into T1 channels [0,11), transposed padded layout (stride 96)
// ---------------------------------------------------------------------------
__global__ __launch_bounds__(256) void stage_x(const float* __restrict__ X,
                                               _Float16* __restrict__ T1, int t) {
    int i = blockIdx.x * 256 + threadIdx.x;   // 2*1024*16
    const int c = i & 15;
    const int pix = (i >> 4) & 1023;
    const int b = i >> 14;
    if (c >= 11 || b >= NB) return;
    const int y = pix >> 5, x = pix & 31;
    const int pp = (y + 2) * PADW + (x + 2);
    T1[((size_t)(b * PPLANE) + pp) * 96 + c] =
        (_Float16)X[(((b * TX + t) * 11 + c) << 10) + pix];
}

// ---------------------------------------------------------------------------
// MFMA ConvLSTM cell v5 (4-wave, 1 block/CU) — used for cell1 only.
// See r9: DMA-staged B double-buffer + A-ring PDA=5 + B-ring depth 3.
// ---------------------------------------------------------------------------
template <int CTOTP, int CH, int NM>
__global__ __launch_bounds__(256) void cell_mfma5(
    const _Float16* __restrict__ T, const _Float16* __restrict__ Wk,
    const float* __restrict__ Bias, float* __restrict__ Cst,
    _Float16* __restrict__ outA, int strideA,
    _Float16* __restrict__ outB, int strideB, float* __restrict__ outP) {
    constexpr int M = 4 * CH;
    constexpr int NCH = CTOTP / 32;
    constexpr int PDA = 5;
    __shared__ _Float16 slab[2 * 896 * 8];

    const int tid = threadIdx.x;
    const int wave = tid >> 6, lane = tid & 63;
    const int l16 = lane & 15, lk = lane >> 4;
    const int wm = wave >> 1, wn = wave & 1;
    const int bid = blockIdx.x;
    const int mtile = bid % NM;
    const int ntile = bid / NM;
    const int nbase = ntile * 64;
    const int b = nbase >> 10;
    const int y0 = (nbase & 1023) >> 5;
    const _Float16* Tb = T + (size_t)(b * PPLANE) * CTOTP;

    f32x4 acc[2][2] = {};

    int bbase[2];
#pragma unroll
    for (int nt = 0; nt < 2; ++nt) {
        const int pxl = wn * 32 + nt * 16 + l16;
        const int r = pxl >> 5, x = pxl & 31;
        bbase[nt] = (((r * 4 + lk) * 36) + x) * 16;
    }
    const int laneAoff = lk * 128 + l16 * 8;

    auto loadA = [&](int cc, int dd, int mt) -> half8 {
        const int mb = mtile * 4 + wm * 2 + mt;
        return *(const half8*)(Wk +
            (size_t)(((dd * (M / 16) + mb) * NCH + cc) * 512 + laneAoff));
    };
    auto stage = [&](int c32) {
        char* dst = (char*)slab + (c32 & 1) * 14336;
#pragma unroll
        for (int k = 0; k < 4; ++k) {
            const int s = wave + k * 4;
            if (s < 14) {
                const int idx = (s << 6) + lane;
                const int col = idx % 36;
                const int rc  = idx / 36;
                const int c8 = rc & 3, rr = rc >> 2;
                const _Float16* src = Tb +
                    (size_t)((y0 + rr) * PADW + col) * CTOTP + c32 * 32 + c8 * 8;
                gload_lds16(src, dst + idx * 16);
            }
        }
    };

    half8 apre[PDA][2];
#pragma unroll
    for (int p = 0; p < PDA; ++p) {
        apre[p][0] = loadA(0, p, 0);
        apre[p][1] = loadA(0, p, 1);
    }
    stage(0);
    __syncthreads();

    for (int c32 = 0; c32 < NCH; ++c32) {
        if (c32 + 1 < NCH) stage(c32 + 1);
        const char* sb = (const char*)slab + (c32 & 1) * 14336;
        half8 bpre[3][2];
#pragma unroll
        for (int p = 0; p < 3; ++p) {
            const int dy = p / 5, dx = p % 5;
            bpre[p][0] = *(const half8*)(sb + bbase[0] + (dy * 144 + dx) * 16);
            bpre[p][1] = *(const half8*)(sb + bbase[1] + (dy * 144 + dx) * 16);
        }
#pragma unroll
        for (int d = 0; d < 25; ++d) {
            const half8 a0 = apre[d % PDA][0];
            const half8 a1 = apre[d % PDA][1];
            const half8 b0 = bpre[d % 3][0];
            const half8 b1 = bpre[d % 3][1];
            {
                const int dp = d + PDA;
                const int cstep = dp / 25;
                const int dd = dp % 25;
                if (cstep == 0 || c32 + 1 < NCH) {
                    const int cc = c32 + cstep;
                    apre[d % PDA][0] = loadA(cc, dd, 0);
                    apre[d % PDA][1] = loadA(cc, dd, 1);
                }
            }
            if (d + 3 < 25) {
                const int dy = (d + 3) / 5, dx = (d + 3) % 5;
                bpre[d % 3][0] = *(const half8*)(sb + bbase[0] + (dy * 144 + dx) * 16);
                bpre[d % 3][1] = *(const half8*)(sb + bbase[1] + (dy * 144 + dx) * 16);
            }
            acc[0][0] = __builtin_amdgcn_mfma_f32_16x16x32_f16(a0, b0, acc[0][0], 0, 0, 0);
            acc[0][1] = __builtin_amdgcn_mfma_f32_16x16x32_f16(a0, b1, acc[0][1], 0, 0, 0);
            acc[1][0] = __builtin_amdgcn_mfma_f32_16x16x32_f16(a1, b0, acc[1][0], 0, 0, 0);
            acc[1][1] = __builtin_amdgcn_mfma_f32_16x16x32_f16(a1, b1, acc[1][1], 0, 0, 0);
        }
        __syncthreads();
    }

#pragma unroll
    for (int mt = 0; mt < 2; ++mt) {
        const int hc = mtile * 16 + wm * 8 + mt * 4 + lk;
        const float bi = Bias[hc], bf = Bias[CH + hc];
        const float bo = Bias[2 * CH + hc], bg = Bias[3 * CH + hc];
#pragma unroll
        for (int nt = 0; nt < 2; ++nt) {
            const int pxl = wn * 32 + nt * 16 + l16;
            const int pix = (nbase & 1023) + pxl;
            const int y = pix >> 5, x = pix & 31;
            const f32x4 a = acc[mt][nt];
            const float gi = a[0] + bi, gf = a[1] + bf;
            const float go = a[2] + bo, gg = a[3] + bg;
            const int idx = ((b * CH + hc) << 10) + pix;
            const float c_old = Cst[idx];
            const float cn = sigf(gf) * c_old + sigf(gi) * tanhf(gg);
            const float hn = sigf(go) * tanhf(cn);
            Cst[idx] = cn;
            const _Float16 hh = (_Float16)hn;
            const size_t pp = (size_t)(b * PPLANE) + (y + 2) * PADW + (x + 2);
            outA[pp * strideA + hc] = hh;
            if (outB) outB[pp * strideB + hc] = hh;
            if (outP) outP[idx] = hn;
        }
    }
}

// ---------------------------------------------------------------------------
// MFMA ConvLSTM cell v7: K-split 8-wave (r12 change). Same 256-block grid
// and per-tap structure as v5, but 512 threads: wave-group 0 (waves 0-3)
// processes even cin-chunks, group 1 odd chunks -> 2 waves/SIMD TLP with
// UNCHANGED total A/B traffic (r11's N-split doubled traffic and halved
// per-tap issue work; this does neither). 4 LDS slab buffers (2 per group).
// Epilogue: group1 writes partial acc to LDS (16KB), group0 adds and runs
// the LSTM update. NCH must be even (cells 2,3: 6,8).
// ---------------------------------------------------------------------------
template <int CTOTP, int CH, int NM>
__global__ __launch_bounds__(512) void cell_mfma7(
    const _Float16* __restrict__ T, const _Float16* __restrict__ Wk,
    const float* __restrict__ Bias, float* __restrict__ Cst,
    _Float16* __restrict__ outA, int strideA,
    _Float16* __restrict__ outB, int strideB, float* __restrict__ outP) {
    constexpr int M = 4 * CH;
    constexpr int NCH = CTOTP / 32;
    constexpr int NH = NCH / 2;          // chunks per group
    constexpr int PDA = 5;
    __shared__ _Float16 slab[4 * 896 * 8];   // 57344 B

    const int tid = threadIdx.x;
    const int wave = tid >> 6, lane = tid & 63;
    const int l16 = lane & 15, lk = lane >> 4;
    const int grp = wave >> 2, w2 = wave & 3;
    const int wm = w2 >> 1, wn = w2 & 1;
    const int bid = blockIdx.x;
    const int mtile = bid % NM;
    const int ntile = bid / NM;
    const int nbase = ntile * 64;
    const int b = nbase >> 10;
    const int y0 = (nbase & 1023) >> 5;
    const _Float16* Tb = T + (size_t)(b * PPLANE) * CTOTP;

    f32x4 acc[2][2] = {};

    int bbase[2];
#pragma unroll
    for (int nt = 0; nt < 2; ++nt) {
        const int pxl = wn * 32 + nt * 16 + l16;
        const int r = pxl >> 5, x = pxl & 31;
        bbase[nt] = (((r * 4 + lk) * 36) + x) * 16;
    }
    const int laneAoff = lk * 128 + l16 * 8;

    auto loadA = [&](int cc, int dd, int mt) -> half8 {
        const int mb = mtile * 4 + wm * 2 + mt;
        return *(const half8*)(Wk +
            (size_t)(((dd * (M / 16) + mb) * NCH + cc) * 512 + laneAoff));
    };
    // stage chunk c32 into explicit buffer bi (0..3); group's waves split segs
    auto stage = [&](int c32, int bi) {
        char* dst = (char*)slab + bi * 14336;
#pragma unroll
        for (int k = 0; k < 4; ++k) {
            const int s = w2 + k * 4;
            if (s < 14) {
                const int idx = (s << 6) + lane;
                const int col = idx % 36;
                const int rc  = idx / 36;
                const int c8 = rc & 3, rr = rc >> 2;
                const _Float16* src = Tb +
                    (size_t)((y0 + rr) * PADW + col) * CTOTP + c32 * 32 + c8 * 8;
                gload_lds16(src, dst + idx * 16);
            }
        }
    };

    // A-ring prologue: taps 0..4 of this group's first chunk (= grp)
    half8 apre[PDA][2];
#pragma unroll
    for (int p = 0; p < PDA; ++p) {
        apre[p][0] = loadA(grp, p, 0);
        apre[p][1] = loadA(grp, p, 1);
    }
    stage(grp, grp * 2);
    __syncthreads();

    for (int i = 0; i < NH; ++i) {
        const int c = 2 * i + grp;
        if (i + 1 < NH) stage(c + 2, grp * 2 + ((i + 1) & 1));
        const char* sb = (const char*)slab + (grp * 2 + (i & 1)) * 14336;
        half8 bpre[3][2];
#pragma unroll
        for (int p = 0; p < 3; ++p) {
            const int dy = p / 5, dx = p % 5;
            bpre[p][0] = *(const half8*)(sb + bbase[0] + (dy * 144 + dx) * 16);
            bpre[p][1] = *(const half8*)(sb + bbase[1] + (dy * 144 + dx) * 16);
        }
#pragma unroll
        for (int d = 0; d < 25; ++d) {
            const half8 a0 = apre[d % PDA][0];
            const half8 a1 = apre[d % PDA][1];
            const half8 b0 = bpre[d % 3][0];
            const half8 b1 = bpre[d % 3][1];
            {
                const int dp = d + PDA;
                const int cstep = dp / 25;          // static 0/1
                const int dd = dp % 25;             // static
                if (cstep == 0 || i + 1 < NH) {
                    const int cc = c + 2 * cstep;   // group stride 2
                    apre[d % PDA][0] = loadA(cc, dd, 0);
                    apre[d % PDA][1] = loadA(cc, dd, 1);
                }
            }
            if (d + 3 < 25) {
                const int dy = (d + 3) / 5, dx = (d + 3) % 5;
                bpre[d % 3][0] = *(const half8*)(sb + bbase[0] + (dy * 144 + dx) * 16);
                bpre[d % 3][1] = *(const half8*)(sb + bbase[1] + (dy * 144 + dx) * 16);
            }
            acc[0][0] = __builtin_amdgcn_mfma_f32_16x16x32_f16(a0, b0, acc[0][0], 0, 0, 0);
            acc[0][1] = __builtin_amdgcn_mfma_f32_16x16x32_f16(a0, b1, acc[0][1], 0, 0, 0);
            acc[1][0] = __builtin_amdgcn_mfma_f32_16x16x32_f16(a1, b0, acc[1][0], 0, 0, 0);
            acc[1][1] = __builtin_amdgcn_mfma_f32_16x16x32_f16(a1, b1, acc[1][1], 0, 0, 0);
        }
        __syncthreads();
    }

    // Cross-group accumulator reduction via LDS (reuse slab; 16KB).
    float* red = (float*)slab;
    const int tig = tid & 255;              // thread index within group
    if (grp == 1) {
#pragma unroll
        for (int mt = 0; mt < 2; ++mt)
#pragma unroll
            for (int nt = 0; nt < 2; ++nt)
                *(f32x4*)(red + tig * 16 + (mt * 2 + nt) * 4) = acc[mt][nt];
    }
    __syncthreads();
    if (grp == 1) return;
#pragma unroll
    for (int mt = 0; mt < 2; ++mt)
#pragma unroll
        for (int nt = 0; nt < 2; ++nt)
            acc[mt][nt] += *(const f32x4*)(red + tig * 16 + (mt * 2 + nt) * 4);

    // Epilogue (group 0 only): lane-local LSTM update.
#pragma unroll
    for (int mt = 0; mt < 2; ++mt) {
        const int hc = mtile * 16 + wm * 8 + mt * 4 + lk;
        const float bi = Bias[hc], bf = Bias[CH + hc];
        const float bo = Bias[2 * CH + hc], bg = Bias[3 * CH + hc];
#pragma unroll
        for (int nt = 0; nt < 2; ++nt) {
            const int pxl = wn * 32 + nt * 16 + l16;
            const int pix = (nbase & 1023) + pxl;
            const int y = pix >> 5, x = pix & 31;
            const f32x4 a = acc[mt][nt];
            const float gi = a[0] + bi, gf = a[1] + bf;
            const float go = a[2] + bo, gg = a[3] + bg;
            const int idx = ((b * CH + hc) << 10) + pix;
            const float c_old = Cst[idx];
            const float cn = sigf(gf) * c_old + sigf(gi) * tanhf(gg);
            const float hn = sigf(go) * tanhf(cn);
            Cst[idx] = cn;
            const _Float16 hh = (_Float16)hn;
            const size_t pp = (size_t)(b * PPLANE) + (y + 2) * PADW + (x + 2);
            outA[pp * strideA + hc] = hh;
            if (outB) outB[pp * strideB + hc] = hh;
            if (outP) outP[idx] = hn;
        }
    }
}

// ---------------------------------------------------------------------------
// head kernel v2 (512 threads): fused meo + aqi + stage_x(t+1). (r12 proven)
// ---------------------------------------------------------------------------
__global__ __launch_bounds__(512) void head_kernel(
    const float* __restrict__ H3, const float* __restrict__ Wm,
    const float* __restrict__ bm, const float* __restrict__ Wf1,
    const float* __restrict__ bf1, const float* __restrict__ Wf2,
    const float* __restrict__ bf2, const int* __restrict__ locs,
    const float* __restrict__ X, _Float16* __restrict__ T1nxt,
    float* __restrict__ out, int t) {
    const int bx = blockIdx.x, b = blockIdx.y, tid = threadIdx.x;
    if (bx >= 45) {            // stage x(t+1): 22 blocks, 11264 elems
        if (t + 1 < TX) {
            const int idx = (bx - 45) * 512 + tid;
            const int c = idx >> 10, pix = idx & 1023;
            const int y = pix >> 5, x = pix & 31;
            T1nxt[((size_t)(b * PPLANE) + (y + 2) * PADW + (x + 2)) * 96 + c] =
                (_Float16)X[(((b * TX + t + 1) * 11 + c) << 10) + pix];
        }
        return;
    }
    if (bx >= NSTA) {          // meo: 10 blocks, 5120 elems
        const int idx = (bx - NSTA) * 512 + tid;
        const int oc = idx >> 10, pix = idx & 1023;
        const float* w = Wm + oc * 128;
        const float* h = H3 + ((b * 128) << 10) + pix;
        float a0 = 0.f, a1 = 0.f, a2 = 0.f, a3 = 0.f;
#pragma unroll
        for (int c = 0; c < 128; c += 4) {
            a0 = fmaf(w[c],     h[c << 10],       a0);
            a1 = fmaf(w[c + 1], h[(c + 1) << 10], a1);
            a2 = fmaf(w[c + 2], h[(c + 2) << 10], a2);
            a3 = fmaf(w[c + 3], h[(c + 3) << 10], a3);
        }
        out[2520 + (b * TX + t) * 5120 + idx] = ((a0 + a1) + (a2 + a3)) + bm[oc];
        return;
    }
    // aqi station s = bx
    __shared__ float feats[1152];
    __shared__ float psum[2][256];
    __shared__ float hid[256];
    const int s = bx;
    const int y0 = locs[2 * s], x0 = locs[2 * s + 1];
    for (int k = tid; k < 1152; k += 512) {
        const int c = k / 9, r = k % 9;
        feats[k] = H3[((b * 128 + c) << 10) + (y0 + r / 3) * 32 + (x0 + r % 3)];
    }
    __syncthreads();
    {
        const int h = tid & 255, kh = tid >> 8;
        const int kb = kh * 576;
        float ac[16] = {};
        for (int kk = 0; kk < 576; kk += 16) {
#pragma unroll
            for (int u = 0; u < 16; ++u)
                ac[u] = fmaf(feats[kb + kk + u], Wf1[(kb + kk + u) * 256 + h], ac[u]);
        }
        psum[kh][h] = (((ac[0] + ac[1]) + (ac[2] + ac[3])) +
                       ((ac[4] + ac[5]) + (ac[6] + ac[7]))) +
                      (((ac[8] + ac[9]) + (ac[10] + ac[11])) +
                       ((ac[12] + ac[13]) + (ac[14] + ac[15])));
    }
    __syncthreads();
    if (tid < 256) hid[tid] = tanhf(psum[0][tid] + psum[1][tid] + bf1[tid]);
    __syncthreads();
    if (tid < 6) {
        float ac[8] = {};
#pragma unroll
        for (int k = 0; k < 256; k += 8) {
#pragma unroll
            for (int u = 0; u < 8; ++u)
                ac[u] = fmaf(hid[k + u], Wf2[(k + u) * 6 + tid], ac[u]);
        }
        out[(b * TX + t) * 210 + s * 6 + tid] =
            ((ac[0] + ac[1]) + (ac[2] + ac[3])) +
            ((ac[4] + ac[5]) + (ac[6] + ac[7])) + bf2[tid];
    }
}

// ---------------------------------------------------------------------------
extern "C" void kernel_launch(void* const* d_in, const int* in_sizes, int n_in,
                              void* d_out, int out_size, void* d_ws, size_t ws_size,
                              hipStream_t stream) {
    const float* X   = (const float*)d_in[0];
    const float* W1  = (const float*)d_in[1];
    const float* b1  = (const float*)d_in[2];
    const float* W2  = (const float*)d_in[3];
    const float* b2  = (const float*)d_in[4];
    const float* W3  = (const float*)d_in[5];
    const float* b3  = (const float*)d_in[6];
    const float* Wm  = (const float*)d_in[7];
    const float* bm  = (const float*)d_in[8];
    const float* Wf1 = (const float*)d_in[9];
    const float* bf1 = (const float*)d_in[10];
    const float* Wf2 = (const float*)d_in[11];
    const float* bf2 = (const float*)d_in[12];
    const int* locs  = (const int*)d_in[13];
    float* out = (float*)d_out;

    // Byte-offset allocator, 256B aligned
    char* base = (char*)d_ws;
    size_t off = 0;
    auto alloc = [&](size_t bytes) -> char* {
        char* p = base + off;
        off = (off + bytes + 255) & ~(size_t)255;
        return p;
    };
    // Zeroed region: T buffers (f16), C states (fp32), H3
    _Float16* T1[2]; T1[0] = (_Float16*)alloc(2 * PPLANE * 96 * 2);
                     T1[1] = (_Float16*)alloc(2 * PPLANE * 96 * 2);
    _Float16* T2[2]; T2[0] = (_Float16*)alloc(2 * PPLANE * 192 * 2);
                     T2[1] = (_Float16*)alloc(2 * PPLANE * 192 * 2);
    _Float16* T3[2]; T3[0] = (_Float16*)alloc(2 * PPLANE * 256 * 2);
                     T3[1] = (_Float16*)alloc(2 * PPLANE * 256 * 2);
    float* C1 = (float*)alloc(2 * 64 * 1024 * 4);
    float* C2 = (float*)alloc(2 * 128 * 1024 * 4);
    float* C3 = (float*)alloc(2 * 128 * 1024 * 4);
    float* H3 = (float*)alloc(2 * 128 * 1024 * 4);
    const size_t zero_bytes = off;
    // Non-zeroed: fully written by prep each call
    _Float16* Wk1 = (_Float16*)alloc((size_t)25 * 256 * 96 * 2);
    _Float16* Wk2 = (_Float16*)alloc((size_t)25 * 512 * 192 * 2);
    _Float16* Wk3 = (_Float16*)alloc((size_t)25 * 512 * 256 * 2);

    hipMemsetAsync(d_ws, 0, zero_bytes, stream);

    prep_w2<75, 96, 64><<<dim3((25 * 256 * 96 + 255) / 256), 256, 0, stream>>>(W1, Wk1);
    prep_w2<192, 192, 128><<<dim3((25 * 512 * 192 + 255) / 256), 256, 0, stream>>>(W2, Wk2);
    prep_w2<256, 256, 128><<<dim3((25 * 512 * 256 + 255) / 256), 256, 0, stream>>>(W3, Wk3);

    stage_x<<<dim3(128), 256, 0, stream>>>(X, T1[0], 0);

    for (int t = 0; t < TX; ++t) {
        const int cur = t & 1, nxt = cur ^ 1;
        // cell1: NCH=3 (odd) -> keep v5. T1[cur](96) -> T1[nxt]@11, T2[cur]@0
        cell_mfma5<96, 64, 4><<<dim3(4 * 32), 256, 0, stream>>>(
            T1[cur], Wk1, b1, C1, T1[nxt] + 11, 96, T2[cur] + 0, 192, nullptr);
        // cell2: K-split 8-wave. T2[cur](192) -> T2[nxt]@64, T3[cur]@0
        cell_mfma7<192, 128, 8><<<dim3(8 * 32), 512, 0, stream>>>(
            T2[cur], Wk2, b2, C2, T2[nxt] + 64, 192, T3[cur] + 0, 256, nullptr);
        // cell3: K-split 8-wave. T3[cur](256) -> T3[nxt]@128, plain H3
        cell_mfma7<256, 128, 8><<<dim3(8 * 32), 512, 0, stream>>>(
            T3[cur], Wk3, b3, C3, T3[nxt] + 128, 256, nullptr, 0, H3);
        // heads for t + stage x(t+1) into T1[nxt] (ch 0..10, no race w/ cell1)
        head_kernel<<<dim3(67, NB), 512, 0, stream>>>(
            H3, Wm, bm, Wf1, bf1, Wf2, bf2, locs, X, T1[nxt], out, t);
    }
}

// Round 14
// 409.558 us; speedup vs baseline: 1.8156x; 1.2015x over previous
//
#include <hip/hip_runtime.h>
#include <math.h>

// Problem constants
#define TX 6
#define NB 2
#define NSTA 35
#define PPLANE 1296      // 36*36 padded plane
#define PADW 36

typedef __attribute__((ext_vector_type(8))) _Float16 half8;
typedef __attribute__((ext_vector_type(4))) float f32x4;

__device__ __forceinline__ float sigf(float x) { return 1.0f / (1.0f + __expf(-x)); }

// Async global->LDS DMA, 16B per lane. LDS dest is wave-uniform base + lane*16.
__device__ __forceinline__ void gload_lds16(const void* g, void* l) {
    __builtin_amdgcn_global_load_lds(
        (const __attribute__((address_space(1))) void*)g,
        (__attribute__((address_space(3))) void*)l, 16, 0, 0);
}

// ---------------------------------------------------------------------------
// Weight prep: W (4CH,CTOT,5,5) fp32 gate-block-major ->
// Wk[d][mb][c32][lk][l16][e8] f16 : fragment = 512 f16 (16 m-rows x 32 cin).
// ---------------------------------------------------------------------------
template <int CTOT, int CTOTP, int CH>
__global__ __launch_bounds__(256) void prep_w2(const float* __restrict__ W,
                                               _Float16* __restrict__ Wk) {
    constexpr int M = 4 * CH;
    const int total = 25 * M * CTOTP;
    int i = blockIdx.x * 256 + threadIdx.x;
    if (i >= total) return;
    const int e   = i & 7;
    const int l16 = (i >> 3) & 15;
    const int lk  = (i >> 7) & 3;
    const int c32 = (i >> 9) % (CTOTP / 32);
    const int rest = (i >> 9) / (CTOTP / 32);
    const int mb = rest % (M / 16);
    const int d  = rest / (M / 16);
    const int m = mb * 16 + l16;
    const int cin = c32 * 32 + lk * 8 + e;
    const int hc = m >> 2, g = m & 3;
    float v = 0.f;
    if (cin < CTOT) v = W[((g * CH + hc) * CTOT + cin) * 25 + d];
    Wk[i] = (_Float16)v;
}

// ---------------------------------------------------------------------------
// Stage x_t into T1 channels [0,11), transposed padded layout, stride 128
// ---------------------------------------------------------------------------
__global__ __launch_bounds__(256) void stage_x(const float* __restrict__ X,
                                               _Float16* __restrict__ T1, int t) {
    int i = blockIdx.x * 256 + threadIdx.x;   // 2*1024*16
    const int c = i & 15;
    const int pix = (i >> 4) & 1023;
    const int b = i >> 14;
    if (c >= 11 || b >= NB) return;
    const int y = pix >> 5, x = pix & 31;
    const int pp = (y + 2) * PADW + (x + 2);
    T1[((size_t)(b * PPLANE) + pp) * 128 + c] =
        (_Float16)X[(((b * TX + t) * 11 + c) << 10) + pix];
}

// ---------------------------------------------------------------------------
// MFMA ConvLSTM cell v7 body (K-split 8-wave, r13 proven): wave-group 0
// does even cin-chunks, group 1 odd; 4 LDS slab buffers; LDS acc reduce;
// A-ring PDA=5 (25%5==0), B-ring depth 3. smem must be >= 57344 B.
// ---------------------------------------------------------------------------
template <int CTOTP, int CH, int NM>
__device__ __forceinline__ void cell7_body(
    char* smem, int bid, int tid,
    const _Float16* __restrict__ T, const _Float16* __restrict__ Wk,
    const float* __restrict__ Bias, float* __restrict__ Cst,
    _Float16* __restrict__ outA, int strideA,
    _Float16* __restrict__ outB, int strideB, float* __restrict__ outP) {
    constexpr int M = 4 * CH;
    constexpr int NCH = CTOTP / 32;
    constexpr int NH = NCH / 2;
    constexpr int PDA = 5;

    const int wave = tid >> 6, lane = tid & 63;
    const int l16 = lane & 15, lk = lane >> 4;
    const int grp = wave >> 2, w2 = wave & 3;
    const int wm = w2 >> 1, wn = w2 & 1;
    const int mtile = bid % NM;
    const int ntile = bid / NM;
    const int nbase = ntile * 64;
    const int b = nbase >> 10;
    const int y0 = (nbase & 1023) >> 5;
    const _Float16* Tb = T + (size_t)(b * PPLANE) * CTOTP;

    f32x4 acc[2][2] = {};

    int bbase[2];
#pragma unroll
    for (int nt = 0; nt < 2; ++nt) {
        const int pxl = wn * 32 + nt * 16 + l16;
        const int r = pxl >> 5, x = pxl & 31;
        bbase[nt] = (((r * 4 + lk) * 36) + x) * 16;
    }
    const int laneAoff = lk * 128 + l16 * 8;

    auto loadA = [&](int cc, int dd, int mt) -> half8 {
        const int mb = mtile * 4 + wm * 2 + mt;
        return *(const half8*)(Wk +
            (size_t)(((dd * (M / 16) + mb) * NCH + cc) * 512 + laneAoff));
    };
    auto stage = [&](int c32, int bi) {
        char* dst = smem + bi * 14336;
#pragma unroll
        for (int k = 0; k < 4; ++k) {
            const int s = w2 + k * 4;
            if (s < 14) {
                const int idx = (s << 6) + lane;
                const int col = idx % 36;
                const int rc  = idx / 36;
                const int c8 = rc & 3, rr = rc >> 2;
                const _Float16* src = Tb +
                    (size_t)((y0 + rr) * PADW + col) * CTOTP + c32 * 32 + c8 * 8;
                gload_lds16(src, dst + idx * 16);
            }
        }
    };

    half8 apre[PDA][2];
#pragma unroll
    for (int p = 0; p < PDA; ++p) {
        apre[p][0] = loadA(grp, p, 0);
        apre[p][1] = loadA(grp, p, 1);
    }
    stage(grp, grp * 2);
    __syncthreads();

    for (int i = 0; i < NH; ++i) {
        const int c = 2 * i + grp;
        if (i + 1 < NH) stage(c + 2, grp * 2 + ((i + 1) & 1));
        const char* sb = smem + (grp * 2 + (i & 1)) * 14336;
        half8 bpre[3][2];
#pragma unroll
        for (int p = 0; p < 3; ++p) {
            const int dy = p / 5, dx = p % 5;
            bpre[p][0] = *(const half8*)(sb + bbase[0] + (dy * 144 + dx) * 16);
            bpre[p][1] = *(const half8*)(sb + bbase[1] + (dy * 144 + dx) * 16);
        }
#pragma unroll
        for (int d = 0; d < 25; ++d) {
            const half8 a0 = apre[d % PDA][0];
            const half8 a1 = apre[d % PDA][1];
            const half8 b0 = bpre[d % 3][0];
            const half8 b1 = bpre[d % 3][1];
            {
                const int dp = d + PDA;
                const int cstep = dp / 25;          // static 0/1
                const int dd = dp % 25;             // static
                if (cstep == 0 || i + 1 < NH) {
                    const int cc = c + 2 * cstep;   // group stride 2
                    apre[d % PDA][0] = loadA(cc, dd, 0);
                    apre[d % PDA][1] = loadA(cc, dd, 1);
                }
            }
            if (d + 3 < 25) {
                const int dy = (d + 3) / 5, dx = (d + 3) % 5;
                bpre[d % 3][0] = *(const half8*)(sb + bbase[0] + (dy * 144 + dx) * 16);
                bpre[d % 3][1] = *(const half8*)(sb + bbase[1] + (dy * 144 + dx) * 16);
            }
            acc[0][0] = __builtin_amdgcn_mfma_f32_16x16x32_f16(a0, b0, acc[0][0], 0, 0, 0);
            acc[0][1] = __builtin_amdgcn_mfma_f32_16x16x32_f16(a0, b1, acc[0][1], 0, 0, 0);
            acc[1][0] = __builtin_amdgcn_mfma_f32_16x16x32_f16(a1, b0, acc[1][0], 0, 0, 0);
            acc[1][1] = __builtin_amdgcn_mfma_f32_16x16x32_f16(a1, b1, acc[1][1], 0, 0, 0);
        }
        __syncthreads();
    }

    // Cross-group accumulator reduction via LDS (reuse slab; 16KB).
    float* red = (float*)smem;
    const int tig = tid & 255;
    if (grp == 1) {
#pragma unroll
        for (int mt = 0; mt < 2; ++mt)
#pragma unroll
            for (int nt = 0; nt < 2; ++nt)
                *(f32x4*)(red + tig * 16 + (mt * 2 + nt) * 4) = acc[mt][nt];
    }
    __syncthreads();
    if (grp == 1) return;
#pragma unroll
    for (int mt = 0; mt < 2; ++mt)
#pragma unroll
        for (int nt = 0; nt < 2; ++nt)
            acc[mt][nt] += *(const f32x4*)(red + tig * 16 + (mt * 2 + nt) * 4);

    // Epilogue (group 0): lane-local LSTM update.
#pragma unroll
    for (int mt = 0; mt < 2; ++mt) {
        const int hc = mtile * 16 + wm * 8 + mt * 4 + lk;
        const float bi = Bias[hc], bf = Bias[CH + hc];
        const float bo = Bias[2 * CH + hc], bg = Bias[3 * CH + hc];
#pragma unroll
        for (int nt = 0; nt < 2; ++nt) {
            const int pxl = wn * 32 + nt * 16 + l16;
            const int pix = (nbase & 1023) + pxl;
            const int y = pix >> 5, x = pix & 31;
            const f32x4 a = acc[mt][nt];
            const float gi = a[0] + bi, gf = a[1] + bf;
            const float go = a[2] + bo, gg = a[3] + bg;
            const int idx = ((b * CH + hc) << 10) + pix;
            const float c_old = Cst[idx];
            const float cn = sigf(gf) * c_old + sigf(gi) * tanhf(gg);
            const float hn = sigf(go) * tanhf(cn);
            Cst[idx] = cn;
            const _Float16 hh = (_Float16)hn;
            const size_t pp = (size_t)(b * PPLANE) + (y + 2) * PADW + (x + 2);
            outA[pp * strideA + hc] = hh;
            if (outB) outB[pp * strideB + hc] = hh;
            if (outP) outP[idx] = hn;
        }
    }
}

// Plain cell7 kernel (cell1 t=0, cell2)
template <int CTOTP, int CH, int NM>
__global__ __launch_bounds__(512) void cell7_kernel(
    const _Float16* __restrict__ T, const _Float16* __restrict__ Wk,
    const float* __restrict__ Bias, float* __restrict__ Cst,
    _Float16* __restrict__ outA, int strideA,
    _Float16* __restrict__ outB, int strideB, float* __restrict__ outP) {
    __shared__ char smem[57344];
    cell7_body<CTOTP, CH, NM>(smem, blockIdx.x, threadIdx.x, T, Wk, Bias, Cst,
                              outA, strideA, outB, strideB, outP);
}

// cell7 + fused stage-x(tnext) (extra 44 blocks). Staging writes T1dst
// ch 0..10 (stride 128) — disjoint from everything cell3 touches.
template <int CTOTP, int CH, int NM>
__global__ __launch_bounds__(512) void cell7_stage_kernel(
    const _Float16* __restrict__ T, const _Float16* __restrict__ Wk,
    const float* __restrict__ Bias, float* __restrict__ Cst,
    _Float16* __restrict__ outA, int strideA, float* __restrict__ outP,
    const float* __restrict__ X, _Float16* __restrict__ T1dst, int tnext) {
    __shared__ char smem[57344];
    const int bx = blockIdx.x;
    if (bx >= NM * 32) {
        if (tnext < TX) {
            const int idx = (bx - NM * 32) * 512 + threadIdx.x;  // < 22528
            const int b = idx / 11264;
            const int r = idx - b * 11264;
            const int c = r >> 10, pix = r & 1023;
            const int y = pix >> 5, x = pix & 31;
            T1dst[((size_t)(b * PPLANE) + (y + 2) * PADW + (x + 2)) * 128 + c] =
                (_Float16)X[(((b * TX + tnext) * 11 + c) << 10) + pix];
        }
        return;
    }
    cell7_body<CTOTP, CH, NM>(smem, bx, threadIdx.x, T, Wk, Bias, Cst,
                              outA, strideA, nullptr, 0, outP);
}

// ---------------------------------------------------------------------------
// tail kernel: head(t) (meo+aqi, 90 blocks) + cell1(t+1) (128 blocks).
// cell1(t+1) reads T1[nxt] (h1 from cell1(t), x(t+1) staged in cell3(t)
// dispatch); writes T1[cur]@11 (cell1(t) done reading) and T2[nxt]@0
// (read next at cell2(t+1)) — race-free within this dispatch.
// ---------------------------------------------------------------------------
__global__ __launch_bounds__(512) void tail_kernel(
    const float* __restrict__ H3, const float* __restrict__ Wm,
    const float* __restrict__ bm, const float* __restrict__ Wf1,
    const float* __restrict__ bf1, const float* __restrict__ Wf2,
    const float* __restrict__ bf2, const int* __restrict__ locs,
    float* __restrict__ out, int t,
    const _Float16* __restrict__ T1in, const _Float16* __restrict__ Wk1,
    const float* __restrict__ b1, float* __restrict__ C1,
    _Float16* __restrict__ h1outA, _Float16* __restrict__ h1outB,
    int do_cell1) {
    __shared__ char smem[57344];
    const int bx = blockIdx.x, tid = threadIdx.x;
    if (bx >= 90) {
        if (do_cell1)
            cell7_body<128, 64, 4>(smem, bx - 90, tid, T1in, Wk1, b1, C1,
                                   h1outA, 128, h1outB, 192, nullptr);
        return;
    }
    const int b = bx / 45, hb = bx % 45;
    if (hb >= NSTA) {          // meo: 10 blocks per b
        const int idx = (hb - NSTA) * 512 + tid;
        const int oc = idx >> 10, pix = idx & 1023;
        const float* w = Wm + oc * 128;
        const float* h = H3 + ((b * 128) << 10) + pix;
        float a0 = 0.f, a1 = 0.f, a2 = 0.f, a3 = 0.f;
#pragma unroll
        for (int c = 0; c < 128; c += 4) {
            a0 = fmaf(w[c],     h[c << 10],       a0);
            a1 = fmaf(w[c + 1], h[(c + 1) << 10], a1);
            a2 = fmaf(w[c + 2], h[(c + 2) << 10], a2);
            a3 = fmaf(w[c + 3], h[(c + 3) << 10], a3);
        }
        out[2520 + (b * TX + t) * 5120 + idx] = ((a0 + a1) + (a2 + a3)) + bm[oc];
        return;
    }
    // aqi station s = hb (r12-proven: coalesced Wf1, 2-way k-split x16 accs)
    float* feats = (float*)smem;         // 1152
    float* psum  = feats + 1152;         // 2*256
    float* hid   = psum + 512;           // 256
    const int s = hb;
    const int y0 = locs[2 * s], x0 = locs[2 * s + 1];
    for (int k = tid; k < 1152; k += 512) {
        const int c = k / 9, r = k % 9;
        feats[k] = H3[((b * 128 + c) << 10) + (y0 + r / 3) * 32 + (x0 + r % 3)];
    }
    __syncthreads();
    {
        const int h = tid & 255, kh = tid >> 8;
        const int kb = kh * 576;
        float ac[16] = {};
        for (int kk = 0; kk < 576; kk += 16) {
#pragma unroll
            for (int u = 0; u < 16; ++u)
                ac[u] = fmaf(feats[kb + kk + u], Wf1[(kb + kk + u) * 256 + h], ac[u]);
        }
        psum[kh * 256 + h] = (((ac[0] + ac[1]) + (ac[2] + ac[3])) +
                              ((ac[4] + ac[5]) + (ac[6] + ac[7]))) +
                             (((ac[8] + ac[9]) + (ac[10] + ac[11])) +
                              ((ac[12] + ac[13]) + (ac[14] + ac[15])));
    }
    __syncthreads();
    if (tid < 256) hid[tid] = tanhf(psum[tid] + psum[256 + tid] + bf1[tid]);
    __syncthreads();
    if (tid < 6) {
        float ac[8] = {};
#pragma unroll
        for (int k = 0; k < 256; k += 8) {
#pragma unroll
            for (int u = 0; u < 8; ++u)
                ac[u] = fmaf(hid[k + u], Wf2[(k + u) * 6 + tid], ac[u]);
        }
        out[(b * TX + t) * 210 + s * 6 + tid] =
            ((ac[0] + ac[1]) + (ac[2] + ac[3])) +
            ((ac[4] + ac[5]) + (ac[6] + ac[7])) + bf2[tid];
    }
}

// ---------------------------------------------------------------------------
extern "C" void kernel_launch(void* const* d_in, const int* in_sizes, int n_in,
                              void* d_out, int out_size, void* d_ws, size_t ws_size,
                              hipStream_t stream) {
    const float* X   = (const float*)d_in[0];
    const float* W1  = (const float*)d_in[1];
    const float* b1  = (const float*)d_in[2];
    const float* W2  = (const float*)d_in[3];
    const float* b2  = (const float*)d_in[4];
    const float* W3  = (const float*)d_in[5];
    const float* b3  = (const float*)d_in[6];
    const float* Wm  = (const float*)d_in[7];
    const float* bm  = (const float*)d_in[8];
    const float* Wf1 = (const float*)d_in[9];
    const float* bf1 = (const float*)d_in[10];
    const float* Wf2 = (const float*)d_in[11];
    const float* bf2 = (const float*)d_in[12];
    const int* locs  = (const int*)d_in[13];
    float* out = (float*)d_out;

    // Byte-offset allocator, 256B aligned
    char* base = (char*)d_ws;
    size_t off = 0;
    auto alloc = [&](size_t bytes) -> char* {
        char* p = base + off;
        off = (off + bytes + 255) & ~(size_t)255;
        return p;
    };
    // Zeroed region: T buffers (f16; T1 now stride 128), C states, H3
    _Float16* T1[2]; T1[0] = (_Float16*)alloc(2 * PPLANE * 128 * 2);
                     T1[1] = (_Float16*)alloc(2 * PPLANE * 128 * 2);
    _Float16* T2[2]; T2[0] = (_Float16*)alloc(2 * PPLANE * 192 * 2);
                     T2[1] = (_Float16*)alloc(2 * PPLANE * 192 * 2);
    _Float16* T3[2]; T3[0] = (_Float16*)alloc(2 * PPLANE * 256 * 2);
                     T3[1] = (_Float16*)alloc(2 * PPLANE * 256 * 2);
    float* C1 = (float*)alloc(2 * 64 * 1024 * 4);
    float* C2 = (float*)alloc(2 * 128 * 1024 * 4);
    float* C3 = (float*)alloc(2 * 128 * 1024 * 4);
    float* H3 = (float*)alloc(2 * 128 * 1024 * 4);
    const size_t zero_bytes = off;
    // Non-zeroed: fully written by prep each call (Wk1 padded to CTOTP=128)
    _Float16* Wk1 = (_Float16*)alloc((size_t)25 * 256 * 128 * 2);
    _Float16* Wk2 = (_Float16*)alloc((size_t)25 * 512 * 192 * 2);
    _Float16* Wk3 = (_Float16*)alloc((size_t)25 * 512 * 256 * 2);

    hipMemsetAsync(d_ws, 0, zero_bytes, stream);

    prep_w2<75, 128, 64><<<dim3((25 * 256 * 128 + 255) / 256), 256, 0, stream>>>(W1, Wk1);
    prep_w2<192, 192, 128><<<dim3((25 * 512 * 192 + 255) / 256), 256, 0, stream>>>(W2, Wk2);
    prep_w2<256, 256, 128><<<dim3((25 * 512 * 256 + 255) / 256), 256, 0, stream>>>(W3, Wk3);

    stage_x<<<dim3(128), 256, 0, stream>>>(X, T1[0], 0);
    // cell1(0): T1[0] -> h1 to T1[1]@11 (stride 128) and T2[0]@0
    cell7_kernel<128, 64, 4><<<dim3(128), 512, 0, stream>>>(
        T1[0], Wk1, b1, C1, T1[1] + 11, 128, T2[0] + 0, 192, nullptr);

    for (int t = 0; t < TX; ++t) {
        const int cur = t & 1, nxt = cur ^ 1;
        // cell2(t): T2[cur] -> T2[nxt]@64, T3[cur]@0
        cell7_kernel<192, 128, 8><<<dim3(256), 512, 0, stream>>>(
            T2[cur], Wk2, b2, C2, T2[nxt] + 64, 192, T3[cur] + 0, 256, nullptr);
        // cell3(t) + stage x(t+1) into T1[nxt] ch0..10
        cell7_stage_kernel<256, 128, 8><<<dim3(300), 512, 0, stream>>>(
            T3[cur], Wk3, b3, C3, T3[nxt] + 128, 256, H3, X, T1[nxt], t + 1);
        // head(t) + cell1(t+1): cell1 reads T1[nxt], writes T1[cur]@11, T2[nxt]@0
        const int do_c1 = (t + 1 < TX);
        tail_kernel<<<dim3(do_c1 ? 218 : 90), 512, 0, stream>>>(
            H3, Wm, bm, Wf1, bf1, Wf2, bf2, locs, out, t,
            T1[nxt], Wk1, b1, C1, T1[cur] + 11, T2[nxt] + 0, do_c1);
    }
}